// Round 7
// baseline (1059.763 us; speedup 1.0000x reference)
//
#include <hip/hip_runtime.h>

#define NN 100000
#define EE 600000
#define DD 128
#define LL 5
#define CTROWS 5152   // 2*2*23*8*7 combined edge-feature rows
#define MBLK 1563     // ceil(NN/64): mlp blocks (64 rows each)
#define SBLK 98       // scan blocks: 98*1024 >= NN

typedef float f32x4 __attribute__((ext_vector_type(4)));
typedef _Float16 f16x8 __attribute__((ext_vector_type(8)));

// ---------------- seed: h = sum of 6 atom-feature embeddings (fp16 out) ------
__global__ __launch_bounds__(256) void seed_kernel(
    const int* __restrict__ an, const int* __restrict__ fc,
    const int* __restrict__ ct, const int* __restrict__ hy,
    const int* __restrict__ nh, const int* __restrict__ ar,
    const float* __restrict__ ean, const float* __restrict__ efc,
    const float* __restrict__ ect, const float* __restrict__ ehy,
    const float* __restrict__ enh, const float* __restrict__ ear,
    _Float16* __restrict__ h)
{
    int idx = blockIdx.x * 256 + threadIdx.x;   // NN*16 exactly
    int n = idx >> 4, q = idx & 15;
    f32x4 a0 = ((const f32x4*)(ean + an[n] * DD))[2 * q];
    f32x4 a1 = ((const f32x4*)(ean + an[n] * DD))[2 * q + 1];
    a0 += ((const f32x4*)(efc + fc[n] * DD))[2 * q];
    a1 += ((const f32x4*)(efc + fc[n] * DD))[2 * q + 1];
    a0 += ((const f32x4*)(ect + ct[n] * DD))[2 * q];
    a1 += ((const f32x4*)(ect + ct[n] * DD))[2 * q + 1];
    a0 += ((const f32x4*)(ehy + hy[n] * DD))[2 * q];
    a1 += ((const f32x4*)(ehy + hy[n] * DD))[2 * q + 1];
    a0 += ((const f32x4*)(enh + nh[n] * DD))[2 * q];
    a1 += ((const f32x4*)(enh + nh[n] * DD))[2 * q + 1];
    a0 += ((const f32x4*)(ear + ar[n] * DD))[2 * q];
    a1 += ((const f32x4*)(ear + ar[n] * DD))[2 * q + 1];
    f16x8 o;
    #pragma unroll
    for (int j = 0; j < 4; ++j) { o[j] = (_Float16)a0[j]; o[j + 4] = (_Float16)a1[j]; }
    ((f16x8*)h)[idx] = o;
}

// ---------------- weight convert+transpose to fp16 [n][k] (both W1,W2) ------
__global__ __launch_bounds__(256) void convw_kernel(const float* __restrict__ w1,
                                                    const float* __restrict__ w2,
                                                    _Float16* __restrict__ w1t,
                                                    _Float16* __restrict__ w2t)
{
    int idx = blockIdx.x * 256 + threadIdx.x;   // 2*5*32768
    int half = idx >= LL * 32768;
    int i = idx - half * LL * 32768;
    int l = i >> 15, rem = i & 32767;
    if (!half) {
        int n = rem >> 7, k = rem & 127;
        w1t[i] = (_Float16)w1[l * 32768 + k * 256 + n];
    } else {
        int n = rem >> 8, k = rem & 255;
        w2t[i] = (_Float16)w2[l * 32768 + k * 128 + n];
    }
}

// ---------------- identity scale/shift for layer-0 gather ----------------
__global__ void idss_kernel(float* __restrict__ idss)
{
    int t = threadIdx.x;
    idss[t] = (t < 128) ? 1.0f : 0.0f;
}

// ---------------- CSR build: count, 3-phase scan, fill ----------------
__global__ __launch_bounds__(256) void count_kernel(const int* __restrict__ ei,
                                                    int* __restrict__ cursor)
{
    int e = blockIdx.x * 256 + threadIdx.x;
    if (e < EE) atomicAdd(&cursor[ei[EE + e]], 1);
}

__global__ __launch_bounds__(1024) void btot_kernel(const int* __restrict__ cursor,
                                                    int* __restrict__ btot)
{
    __shared__ int wsum[16];
    int tid = threadIdx.x;
    int i = blockIdx.x * 1024 + tid;
    int x = (i < NN) ? cursor[i] : 0;
    #pragma unroll
    for (int off = 1; off < 64; off <<= 1) x += __shfl_xor(x, off, 64);
    if ((tid & 63) == 0) wsum[tid >> 6] = x;
    __syncthreads();
    if (tid == 0) {
        int s = 0;
        #pragma unroll
        for (int w = 0; w < 16; ++w) s += wsum[w];
        btot[blockIdx.x] = s;
    }
}

__global__ __launch_bounds__(128) void bscan_kernel(const int* __restrict__ btot,
                                                    int* __restrict__ boff,
                                                    int* __restrict__ rowstart)
{
    __shared__ int w0;
    int t = threadIdx.x;
    int lane = t & 63, wv = t >> 6;
    int x = (t < SBLK) ? btot[t] : 0;
    int incl = x;
    #pragma unroll
    for (int off = 1; off < 64; off <<= 1) {
        int u = __shfl_up(incl, off, 64);
        if (lane >= off) incl += u;
    }
    if (wv == 0 && lane == 63) w0 = incl;
    __syncthreads();
    if (wv == 1) incl += w0;
    if (t < SBLK) boff[t] = incl - x;
    if (t == 127) rowstart[NN] = incl;   // grand total
}

__global__ __launch_bounds__(1024) void apply_kernel(const int* __restrict__ cursorin,
                                                     const int* __restrict__ boff,
                                                     int* __restrict__ rowstart,
                                                     int* __restrict__ cursor)
{
    __shared__ int wsum[16];
    int tid = threadIdx.x;
    int lane = tid & 63, wv = tid >> 6;
    int i = blockIdx.x * 1024 + tid;
    int x = (i < NN) ? cursorin[i] : 0;
    int incl = x;
    #pragma unroll
    for (int off = 1; off < 64; off <<= 1) {
        int u = __shfl_up(incl, off, 64);
        if (lane >= off) incl += u;
    }
    if (lane == 63) wsum[wv] = incl;
    __syncthreads();
    int pre = 0;
    #pragma unroll
    for (int w = 0; w < 16; ++w) pre += (w < wv) ? wsum[w] : 0;
    int excl = boff[blockIdx.x] + pre + incl - x;
    if (i < NN) { rowstart[i] = excl; cursor[i] = excl; }
}

__global__ __launch_bounds__(256) void fill_kernel(
    const int* __restrict__ ei, int* __restrict__ cursor, int* __restrict__ rec,
    const int* __restrict__ f0, const int* __restrict__ f1,
    const int* __restrict__ f2, const int* __restrict__ f3,
    const int* __restrict__ f4)
{
    int e = blockIdx.x * 256 + threadIdx.x;
    if (e >= EE) return;
    int dst = ei[EE + e];
    int p = atomicAdd(&cursor[dst], 1);
    int f = f0[e] + 2 * (f1[e] + 2 * (f2[e] + 23 * (f3[e] + 8 * f4[e])));
    rec[p] = ei[e] | (f << 17);
}

// ---------------- combined edge-embedding table, ALL layers (fp16) ----------
__global__ __launch_bounds__(256) void ctab_kernel(
    const float* __restrict__ ec, const float* __restrict__ ea,
    const float* __restrict__ eb, const float* __restrict__ ed,
    const float* __restrict__ es, _Float16* __restrict__ ctab)
{
    int idx = blockIdx.x * 256 + threadIdx.x;   // LL*CTROWS*16 exactly
    int row = idx >> 4, q = idx & 15;
    int l = row / CTROWS, rl = row - l * CTROWS;
    int conj = rl & 1, arom = (rl >> 1) & 1;
    int r2 = rl >> 2;
    int bt = r2 % 23, r3 = r2 / 23;
    int bd = r3 & 7, bs = r3 >> 3;
    const float* pc = ec + (l * 3 + conj) * DD;
    const float* pa = ea + (l * 3 + arom) * DD;
    const float* pb = eb + (l * 23 + bt) * DD;
    const float* pd = ed + (l * 8 + bd) * DD;
    const float* ps = es + (l * 7 + bs) * DD;
    f32x4 a0 = ((const f32x4*)pc)[2 * q] + ((const f32x4*)pa)[2 * q]
             + ((const f32x4*)pb)[2 * q] + ((const f32x4*)pd)[2 * q]
             + ((const f32x4*)ps)[2 * q];
    f32x4 a1 = ((const f32x4*)pc)[2 * q + 1] + ((const f32x4*)pa)[2 * q + 1]
             + ((const f32x4*)pb)[2 * q + 1] + ((const f32x4*)pd)[2 * q + 1]
             + ((const f32x4*)ps)[2 * q + 1];
    f16x8 o;
    #pragma unroll
    for (int j = 0; j < 4; ++j) { o[j] = (_Float16)a0[j]; o[j + 4] = (_Float16)a1[j]; }
    ((f16x8*)ctab)[idx] = o;
}

// ---------------- gather-aggregate with fused BN(+relu), fp16 in/out ---------
__global__ __launch_bounds__(256) void gather_bn_kernel(
    const _Float16* __restrict__ hsrc, _Float16* __restrict__ agg,
    const int* __restrict__ rowstart, const int* __restrict__ rec,
    const _Float16* __restrict__ ctab, const float* __restrict__ ss, int dorelu)
{
    int idx = blockIdx.x * 256 + threadIdx.x;   // NN*16
    int n = idx >> 4, q = idx & 15;
    f32x4 sc0 = ((const f32x4*)ss)[2 * q],        sc1 = ((const f32x4*)ss)[2 * q + 1];
    f32x4 sh0 = ((const f32x4*)(ss + 128))[2 * q], sh1 = ((const f32x4*)(ss + 128))[2 * q + 1];
    int p0 = rowstart[n], p1 = rowstart[n + 1];
    f16x8 x = ((const f16x8*)hsrc)[idx];
    f16x8 c0 = ((const f16x8*)ctab)[q];           // self_vec == ctab row 0
    float v[8];
    #pragma unroll
    for (int j = 0; j < 8; ++j) {
        float sc = (j < 4) ? sc0[j] : sc1[j - 4];
        float sh = (j < 4) ? sh0[j] : sh1[j - 4];
        float t = (float)x[j] * sc + sh;
        if (dorelu && t < 0.f) t = 0.f;
        v[j] = t + (float)c0[j];
    }
    int p = p0;
    for (; p + 2 <= p1; p += 2) {                 // 2-edge unroll: overlap loads
        int ra = rec[p], rb = rec[p + 1];
        int sa = ra & 0x1FFFF, sb = rb & 0x1FFFF;
        int fa = ((unsigned)ra) >> 17, fb = ((unsigned)rb) >> 17;
        f16x8 ya = *(const f16x8*)(hsrc + sa * DD + q * 8);
        f16x8 ea = *(const f16x8*)(ctab + fa * DD + q * 8);
        f16x8 yb = *(const f16x8*)(hsrc + sb * DD + q * 8);
        f16x8 eb = *(const f16x8*)(ctab + fb * DD + q * 8);
        #pragma unroll
        for (int j = 0; j < 8; ++j) {
            float sc = (j < 4) ? sc0[j] : sc1[j - 4];
            float sh = (j < 4) ? sh0[j] : sh1[j - 4];
            float ta = (float)ya[j] * sc + sh;
            float tb = (float)yb[j] * sc + sh;
            if (dorelu) { if (ta < 0.f) ta = 0.f; if (tb < 0.f) tb = 0.f; }
            v[j] += ta + tb + (float)ea[j] + (float)eb[j];
        }
    }
    if (p < p1) {
        int r = rec[p];
        int s = r & 0x1FFFF;
        int f = ((unsigned)r) >> 17;
        f16x8 y = *(const f16x8*)(hsrc + s * DD + q * 8);
        f16x8 e = *(const f16x8*)(ctab + f * DD + q * 8);
        #pragma unroll
        for (int j = 0; j < 8; ++j) {
            float sc = (j < 4) ? sc0[j] : sc1[j - 4];
            float sh = (j < 4) ? sh0[j] : sh1[j - 4];
            float t = (float)y[j] * sc + sh;
            if (dorelu && t < 0.f) t = 0.f;
            v[j] += t + (float)e[j];
        }
    }
    f16x8 o;
    #pragma unroll
    for (int j = 0; j < 8; ++j) o[j] = (_Float16)v[j];
    ((f16x8*)agg)[idx] = o;
}

// ---------------- fused MLP v4: barrier-free, weights direct from L1/L2 ------
// Weights are identical for all blocks (128 KB/layer, cache-resident): each
// lane's B-frag is a contiguous 16B global load — no LDS staging, no
// __syncthreads in the compute path. hid tile is wave-private LDS (lgkm-
// ordered within the wave). One barrier remains for the stats epilogue.
__global__ __launch_bounds__(256) void mlp_kernel(
    const _Float16* __restrict__ A, const _Float16* __restrict__ w1t,
    const _Float16* __restrict__ w2t,
    const float* __restrict__ b1, const float* __restrict__ b2,
    _Float16* __restrict__ hpre, float* __restrict__ psum, float* __restrict__ psq,
    int M)
{
    __shared__ _Float16 hid[4 * 16 * 264];   // per-wave 16 rows x (256+8 pad)
    __shared__ float red[1024];              // cross-wave stat reduce
    int tid = threadIdx.x;
    int wave = tid >> 6, lane = tid & 63;
    int ln = lane & 15, quad = lane >> 4;
    int wrow0 = blockIdx.x * 64 + wave * 16;
    int m = wrow0 + ln;
    bool valid = m < M;
    _Float16* hw = &hid[wave * 16 * 264];

    f16x8 af[4];
    #pragma unroll
    for (int kb = 0; kb < 4; ++kb) {
        f16x8 a = {};
        if (valid) a = *(const f16x8*)(A + m * 128 + kb * 32 + quad * 8);
        af[kb] = a;
    }

    // GEMM1: hid[16x256 per wave] = relu(A @ W1 + b1)
    #pragma unroll 1
    for (int nc = 0; nc < 4; ++nc) {
        f32x4 acc1[4] = {};
        #pragma unroll
        for (int kb = 0; kb < 4; ++kb) {
            #pragma unroll
            for (int nt = 0; nt < 4; ++nt) {
                f16x8 wf = *(const f16x8*)(w1t + (nc * 64 + nt * 16 + ln) * 128 + kb * 32 + quad * 8);
                acc1[nt] = __builtin_amdgcn_mfma_f32_16x16x32_f16(af[kb], wf, acc1[nt], 0, 0, 0);
            }
        }
        #pragma unroll
        for (int nt = 0; nt < 4; ++nt) {
            float bias = b1[nc * 64 + nt * 16 + ln];
            #pragma unroll
            for (int r = 0; r < 4; ++r) {
                float v = acc1[nt][r] + bias;
                v = v > 0.f ? v : 0.f;
                hw[(quad * 4 + r) * 264 + nc * 64 + nt * 16 + ln] = (_Float16)v;
            }
        }
    }

    // GEMM2: acc2 = hid @ W2 (wave-private hid, lgkm-ordered; no barrier)
    f32x4 acc2[8] = {};
    #pragma unroll 2
    for (int kb2 = 0; kb2 < 8; ++kb2) {
        f16x8 a2 = *(const f16x8*)(&hw[ln * 264 + kb2 * 32 + quad * 8]);
        #pragma unroll
        for (int nt2 = 0; nt2 < 8; ++nt2) {
            f16x8 wf = *(const f16x8*)(w2t + (nt2 * 16 + ln) * 256 + kb2 * 32 + quad * 8);
            acc2[nt2] = __builtin_amdgcn_mfma_f32_16x16x32_f16(a2, wf, acc2[nt2], 0, 0, 0);
        }
    }

    // epilogue: bias, store hpre, per-block column partial sums (no atomics)
    #pragma unroll
    for (int nt2 = 0; nt2 < 8; ++nt2) {
        int n2 = nt2 * 16 + ln;
        float bias = b2[n2];
        float s = 0.f, q = 0.f;
        #pragma unroll
        for (int r = 0; r < 4; ++r) {
            int row = wrow0 + quad * 4 + r;
            if (row < M) {
                float v = acc2[nt2][r] + bias;
                hpre[row * 128 + n2] = (_Float16)v;
                s += v; q += v * v;
            }
        }
        s += __shfl_xor(s, 16, 64); s += __shfl_xor(s, 32, 64);
        q += __shfl_xor(q, 16, 64); q += __shfl_xor(q, 32, 64);
        if (quad == 0) {
            red[wave * 128 + n2] = s;
            red[512 + wave * 128 + n2] = q;
        }
    }
    __syncthreads();
    if (tid < 128) {
        float s = red[tid] + red[128 + tid] + red[256 + tid] + red[384 + tid];
        psum[blockIdx.x * 128 + tid] = s;
    } else {
        int c = tid - 128;
        float q = red[512 + c] + red[640 + c] + red[768 + c] + red[896 + c];
        psq[blockIdx.x * 128 + c] = q;
    }
}

// ---------------- fold partials -> scale/shift for BN ----------------
__global__ __launch_bounds__(256) void reduce_kernel(
    const float* __restrict__ psum, const float* __restrict__ psq,
    const float* __restrict__ gamma, const float* __restrict__ beta,
    float* __restrict__ ss, int nblk)
{
    int c = blockIdx.x;                  // 0..127
    int tid = threadIdx.x;
    float s = 0.f, q = 0.f;
    for (int b = tid; b < nblk; b += 256) {
        s += psum[b * 128 + c];
        q += psq[b * 128 + c];
    }
    #pragma unroll
    for (int off = 1; off < 64; off <<= 1) {
        s += __shfl_xor(s, off, 64);
        q += __shfl_xor(q, off, 64);
    }
    __shared__ float rs[4], rq[4];
    int wave = tid >> 6;
    if ((tid & 63) == 0) { rs[wave] = s; rq[wave] = q; }
    __syncthreads();
    if (tid == 0) {
        s = rs[0] + rs[1] + rs[2] + rs[3];
        q = rq[0] + rq[1] + rq[2] + rq[3];
        const float invN = 1.0f / NN;
        float mean = s * invN;
        float var = q * invN - mean * mean;
        float inv = rsqrtf(var + 1e-5f);
        float scale = gamma[c] * inv;
        ss[c] = scale;
        ss[128 + c] = beta[c] - mean * scale;
    }
}

// ---------------- final BN apply (no relu) -> fp32 d_out ----------------
__global__ __launch_bounds__(256) void final_bn_kernel(
    const _Float16* __restrict__ hpre, float* __restrict__ out,
    const float* __restrict__ ss)
{
    int idx = blockIdx.x * 256 + threadIdx.x;   // NN*16
    int q = idx & 15;
    f16x8 x = ((const f16x8*)hpre)[idx];
    f32x4 sc0 = ((const f32x4*)ss)[2 * q],        sc1 = ((const f32x4*)ss)[2 * q + 1];
    f32x4 sh0 = ((const f32x4*)(ss + 128))[2 * q], sh1 = ((const f32x4*)(ss + 128))[2 * q + 1];
    f32x4 y0, y1;
    #pragma unroll
    for (int j = 0; j < 4; ++j) {
        y0[j] = (float)x[j] * sc0[j] + sh0[j];
        y1[j] = (float)x[j + 4] * sc1[j] + sh1[j];
    }
    ((f32x4*)out)[2 * idx] = y0;
    ((f32x4*)out)[2 * idx + 1] = y1;
}

extern "C" void kernel_launch(void* const* d_in, const int* in_sizes, int n_in,
                              void* d_out, int out_size, void* d_ws, size_t ws_size,
                              hipStream_t stream)
{
    const int* an  = (const int*)d_in[0];
    const int* fc  = (const int*)d_in[1];
    const int* ct  = (const int*)d_in[2];
    const int* hy  = (const int*)d_in[3];
    const int* nh  = (const int*)d_in[4];
    const int* ar  = (const int*)d_in[5];
    const int* ei  = (const int*)d_in[6];
    const int* econ = (const int*)d_in[7];
    const int* earo = (const int*)d_in[8];
    const int* ebt  = (const int*)d_in[9];
    const int* ebd  = (const int*)d_in[10];
    const int* ebs  = (const int*)d_in[11];
    const float* ean = (const float*)d_in[12];
    const float* efc = (const float*)d_in[13];
    const float* ect = (const float*)d_in[14];
    const float* ehy = (const float*)d_in[15];
    const float* enh = (const float*)d_in[16];
    const float* ear = (const float*)d_in[17];
    const float* e_conj   = (const float*)d_in[18];
    const float* e_arom   = (const float*)d_in[19];
    const float* e_btype  = (const float*)d_in[20];
    const float* e_bdir   = (const float*)d_in[21];
    const float* e_bstereo= (const float*)d_in[22];
    const float* mlp_w1 = (const float*)d_in[23];
    const float* mlp_b1 = (const float*)d_in[24];
    const float* mlp_w2 = (const float*)d_in[25];
    const float* mlp_b2 = (const float*)d_in[26];
    const float* bn_gamma = (const float*)d_in[27];
    const float* bn_beta  = (const float*)d_in[28];

    // workspace carve (base 256B-aligned; all segments stay 16B-aligned)
    _Float16* h0    = (_Float16*)d_ws;                  // N*128 fp16
    _Float16* agg   = h0 + (size_t)NN * DD;             // N*128 fp16
    _Float16* hpre  = agg + (size_t)NN * DD;            // N*128 fp16
    _Float16* w1t   = hpre + (size_t)NN * DD;           // 5*256*128 fp16
    _Float16* w2t   = w1t + LL * 256 * 128;             // 5*128*256 fp16
    _Float16* ctabL = w2t + LL * 128 * 256;             // LL*CTROWS*128 fp16
    float*    psum  = (float*)(ctabL + (size_t)LL * CTROWS * DD);  // MBLK*128
    float*    psq   = psum + MBLK * 128;                // MBLK*128
    float*    ss    = psq + MBLK * 128;                 // 256 (scale|shift)
    float*    idss  = ss + 256;                         // 256 identity
    int* rowstart = (int*)(idss + 256);                 // NN+1
    int* cursor   = rowstart + NN + 8;                  // NN
    int* rec      = cursor + NN;                        // EE
    int* btot     = rec + EE;                           // SBLK
    int* boff     = btot + SBLK + 8;                    // SBLK
    // total ~= 93 MB

    convw_kernel<<<1280, 256, 0, stream>>>(mlp_w1, mlp_w2, w1t, w2t);
    seed_kernel<<<6250, 256, 0, stream>>>(an, fc, ct, hy, nh, ar,
                                          ean, efc, ect, ehy, enh, ear, h0);
    idss_kernel<<<1, 256, 0, stream>>>(idss);
    ctab_kernel<<<1610, 256, 0, stream>>>(e_conj, e_arom, e_btype, e_bdir,
                                          e_bstereo, ctabL);

    // CSR build (re-run every call: ws is re-poisoned)
    hipMemsetAsync(cursor, 0, NN * sizeof(int), stream);
    count_kernel<<<2344, 256, 0, stream>>>(ei, cursor);
    btot_kernel<<<SBLK, 1024, 0, stream>>>(cursor, btot);
    bscan_kernel<<<1, 128, 0, stream>>>(btot, boff, rowstart);
    apply_kernel<<<SBLK, 1024, 0, stream>>>(cursor, boff, rowstart, cursor);
    fill_kernel<<<2344, 256, 0, stream>>>(ei, cursor, rec,
                                          econ, earo, ebt, ebd, ebs);

    for (int l = 0; l < LL; ++l) {
        gather_bn_kernel<<<6250, 256, 0, stream>>>(
            (l == 0) ? h0 : hpre, agg, rowstart, rec,
            ctabL + (size_t)l * CTROWS * DD,
            (l == 0) ? idss : ss, (l == 0) ? 0 : 1);
        mlp_kernel<<<MBLK, 256, 0, stream>>>(
            agg, w1t + l * 32768, w2t + l * 32768,
            mlp_b1 + l * 256, mlp_b2 + l * 128,
            hpre, psum, psq, NN);
        reduce_kernel<<<128, 256, 0, stream>>>(
            psum, psq, bn_gamma + l * 128, bn_beta + l * 128, ss, MBLK);
    }
    final_bn_kernel<<<6250, 256, 0, stream>>>(hpre, (float*)d_out, ss);
}

// Round 8
// 753.336 us; speedup vs baseline: 1.4068x; 1.4068x over previous
//
#include <hip/hip_runtime.h>

#define NN 100000
#define EE 600000
#define DD 128
#define LL 5
#define CTROWS 5152   // 2*2*23*8*7 combined edge-feature rows
#define MBLK 1563     // ceil(NN/64): mlp blocks (64 rows each)
#define SBLK 98       // scan blocks: 98*1024 >= NN

typedef float f32x4 __attribute__((ext_vector_type(4)));
typedef _Float16 f16x8 __attribute__((ext_vector_type(8)));
typedef _Float16 f16x4 __attribute__((ext_vector_type(4)));

// ---------------- seed: h = sum of 6 atom-feature embeddings (fp16 out) ------
__global__ __launch_bounds__(256) void seed_kernel(
    const int* __restrict__ an, const int* __restrict__ fc,
    const int* __restrict__ ct, const int* __restrict__ hy,
    const int* __restrict__ nh, const int* __restrict__ ar,
    const float* __restrict__ ean, const float* __restrict__ efc,
    const float* __restrict__ ect, const float* __restrict__ ehy,
    const float* __restrict__ enh, const float* __restrict__ ear,
    _Float16* __restrict__ h)
{
    int idx = blockIdx.x * 256 + threadIdx.x;   // NN*16 exactly
    int n = idx >> 4, q = idx & 15;
    f32x4 a0 = ((const f32x4*)(ean + an[n] * DD))[2 * q];
    f32x4 a1 = ((const f32x4*)(ean + an[n] * DD))[2 * q + 1];
    a0 += ((const f32x4*)(efc + fc[n] * DD))[2 * q];
    a1 += ((const f32x4*)(efc + fc[n] * DD))[2 * q + 1];
    a0 += ((const f32x4*)(ect + ct[n] * DD))[2 * q];
    a1 += ((const f32x4*)(ect + ct[n] * DD))[2 * q + 1];
    a0 += ((const f32x4*)(ehy + hy[n] * DD))[2 * q];
    a1 += ((const f32x4*)(ehy + hy[n] * DD))[2 * q + 1];
    a0 += ((const f32x4*)(enh + nh[n] * DD))[2 * q];
    a1 += ((const f32x4*)(enh + nh[n] * DD))[2 * q + 1];
    a0 += ((const f32x4*)(ear + ar[n] * DD))[2 * q];
    a1 += ((const f32x4*)(ear + ar[n] * DD))[2 * q + 1];
    f16x8 o;
    #pragma unroll
    for (int j = 0; j < 4; ++j) { o[j] = (_Float16)a0[j]; o[j + 4] = (_Float16)a1[j]; }
    ((f16x8*)h)[idx] = o;
}

// ---------------- weight convert+transpose to fp16 [n][k] (both W1,W2) ------
__global__ __launch_bounds__(256) void convw_kernel(const float* __restrict__ w1,
                                                    const float* __restrict__ w2,
                                                    _Float16* __restrict__ w1t,
                                                    _Float16* __restrict__ w2t)
{
    int idx = blockIdx.x * 256 + threadIdx.x;   // 2*5*32768
    int half = idx >= LL * 32768;
    int i = idx - half * LL * 32768;
    int l = i >> 15, rem = i & 32767;
    if (!half) {
        int n = rem >> 7, k = rem & 127;
        w1t[i] = (_Float16)w1[l * 32768 + k * 256 + n];
    } else {
        int n = rem >> 8, k = rem & 255;
        w2t[i] = (_Float16)w2[l * 32768 + k * 128 + n];
    }
}

// ---------------- identity scale/shift for layer-0 gather ----------------
__global__ void idss_kernel(float* __restrict__ idss)
{
    int t = threadIdx.x;
    idss[t] = (t < 128) ? 1.0f : 0.0f;
}

// ---------------- CSR build: count, 3-phase scan, fill ----------------
__global__ __launch_bounds__(256) void count_kernel(const int* __restrict__ ei,
                                                    int* __restrict__ cursor)
{
    int e = blockIdx.x * 256 + threadIdx.x;
    if (e < EE) atomicAdd(&cursor[ei[EE + e]], 1);
}

__global__ __launch_bounds__(1024) void btot_kernel(const int* __restrict__ cursor,
                                                    int* __restrict__ btot)
{
    __shared__ int wsum[16];
    int tid = threadIdx.x;
    int i = blockIdx.x * 1024 + tid;
    int x = (i < NN) ? cursor[i] : 0;
    #pragma unroll
    for (int off = 1; off < 64; off <<= 1) x += __shfl_xor(x, off, 64);
    if ((tid & 63) == 0) wsum[tid >> 6] = x;
    __syncthreads();
    if (tid == 0) {
        int s = 0;
        #pragma unroll
        for (int w = 0; w < 16; ++w) s += wsum[w];
        btot[blockIdx.x] = s;
    }
}

__global__ __launch_bounds__(128) void bscan_kernel(const int* __restrict__ btot,
                                                    int* __restrict__ boff,
                                                    int* __restrict__ rowstart)
{
    __shared__ int w0;
    int t = threadIdx.x;
    int lane = t & 63, wv = t >> 6;
    int x = (t < SBLK) ? btot[t] : 0;
    int incl = x;
    #pragma unroll
    for (int off = 1; off < 64; off <<= 1) {
        int u = __shfl_up(incl, off, 64);
        if (lane >= off) incl += u;
    }
    if (wv == 0 && lane == 63) w0 = incl;
    __syncthreads();
    if (wv == 1) incl += w0;
    if (t < SBLK) boff[t] = incl - x;
    if (t == 127) rowstart[NN] = incl;   // grand total
}

__global__ __launch_bounds__(1024) void apply_kernel(const int* __restrict__ cursorin,
                                                     const int* __restrict__ boff,
                                                     int* __restrict__ rowstart,
                                                     int* __restrict__ cursor)
{
    __shared__ int wsum[16];
    int tid = threadIdx.x;
    int lane = tid & 63, wv = tid >> 6;
    int i = blockIdx.x * 1024 + tid;
    int x = (i < NN) ? cursorin[i] : 0;
    int incl = x;
    #pragma unroll
    for (int off = 1; off < 64; off <<= 1) {
        int u = __shfl_up(incl, off, 64);
        if (lane >= off) incl += u;
    }
    if (lane == 63) wsum[wv] = incl;
    __syncthreads();
    int pre = 0;
    #pragma unroll
    for (int w = 0; w < 16; ++w) pre += (w < wv) ? wsum[w] : 0;
    int excl = boff[blockIdx.x] + pre + incl - x;
    if (i < NN) { rowstart[i] = excl; cursor[i] = excl; }
}

__global__ __launch_bounds__(256) void fill_kernel(
    const int* __restrict__ ei, int* __restrict__ cursor, int* __restrict__ rec,
    const int* __restrict__ f0, const int* __restrict__ f1,
    const int* __restrict__ f2, const int* __restrict__ f3,
    const int* __restrict__ f4)
{
    int e = blockIdx.x * 256 + threadIdx.x;
    if (e >= EE) return;
    int dst = ei[EE + e];
    int p = atomicAdd(&cursor[dst], 1);
    int f = f0[e] + 2 * (f1[e] + 2 * (f2[e] + 23 * (f3[e] + 8 * f4[e])));
    rec[p] = ei[e] | (f << 17);
}

// ---------------- combined edge-embedding table, ALL layers (fp16) ----------
__global__ __launch_bounds__(256) void ctab_kernel(
    const float* __restrict__ ec, const float* __restrict__ ea,
    const float* __restrict__ eb, const float* __restrict__ ed,
    const float* __restrict__ es, _Float16* __restrict__ ctab)
{
    int idx = blockIdx.x * 256 + threadIdx.x;   // LL*CTROWS*16 exactly
    int row = idx >> 4, q = idx & 15;
    int l = row / CTROWS, rl = row - l * CTROWS;
    int conj = rl & 1, arom = (rl >> 1) & 1;
    int r2 = rl >> 2;
    int bt = r2 % 23, r3 = r2 / 23;
    int bd = r3 & 7, bs = r3 >> 3;
    const float* pc = ec + (l * 3 + conj) * DD;
    const float* pa = ea + (l * 3 + arom) * DD;
    const float* pb = eb + (l * 23 + bt) * DD;
    const float* pd = ed + (l * 8 + bd) * DD;
    const float* ps = es + (l * 7 + bs) * DD;
    f32x4 a0 = ((const f32x4*)pc)[2 * q] + ((const f32x4*)pa)[2 * q]
             + ((const f32x4*)pb)[2 * q] + ((const f32x4*)pd)[2 * q]
             + ((const f32x4*)ps)[2 * q];
    f32x4 a1 = ((const f32x4*)pc)[2 * q + 1] + ((const f32x4*)pa)[2 * q + 1]
             + ((const f32x4*)pb)[2 * q + 1] + ((const f32x4*)pd)[2 * q + 1]
             + ((const f32x4*)ps)[2 * q + 1];
    f16x8 o;
    #pragma unroll
    for (int j = 0; j < 4; ++j) { o[j] = (_Float16)a0[j]; o[j + 4] = (_Float16)a1[j]; }
    ((f16x8*)ctab)[idx] = o;
}

// ---------------- gather-aggregate with fused BN(+relu), 4-edge unroll -------
__global__ __launch_bounds__(256) void gather_bn_kernel(
    const _Float16* __restrict__ hsrc, _Float16* __restrict__ agg,
    const int* __restrict__ rowstart, const int* __restrict__ rec,
    const _Float16* __restrict__ ctab, const float* __restrict__ ss, int dorelu)
{
    int idx = blockIdx.x * 256 + threadIdx.x;   // NN*16
    int n = idx >> 4, q = idx & 15;
    f32x4 sc0 = ((const f32x4*)ss)[2 * q],        sc1 = ((const f32x4*)ss)[2 * q + 1];
    f32x4 sh0 = ((const f32x4*)(ss + 128))[2 * q], sh1 = ((const f32x4*)(ss + 128))[2 * q + 1];
    int p0 = rowstart[n], p1 = rowstart[n + 1];
    f16x8 x = ((const f16x8*)hsrc)[idx];
    f16x8 c0 = ((const f16x8*)ctab)[q];           // self_vec == ctab row 0
    float v[8];
    #pragma unroll
    for (int j = 0; j < 8; ++j) {
        float sc = (j < 4) ? sc0[j] : sc1[j - 4];
        float sh = (j < 4) ? sh0[j] : sh1[j - 4];
        float t = (float)x[j] * sc + sh;
        if (dorelu && t < 0.f) t = 0.f;
        v[j] = t + (float)c0[j];
    }
    int p = p0;
    for (; p + 4 <= p1; p += 4) {   // 4-edge unroll: 8 independent loads in flight
        int r0 = rec[p], r1 = rec[p + 1], r2 = rec[p + 2], r3 = rec[p + 3];
        f16x8 y0 = *(const f16x8*)(hsrc + (r0 & 0x1FFFF) * DD + q * 8);
        f16x8 y1 = *(const f16x8*)(hsrc + (r1 & 0x1FFFF) * DD + q * 8);
        f16x8 y2 = *(const f16x8*)(hsrc + (r2 & 0x1FFFF) * DD + q * 8);
        f16x8 y3 = *(const f16x8*)(hsrc + (r3 & 0x1FFFF) * DD + q * 8);
        f16x8 e0 = *(const f16x8*)(ctab + (((unsigned)r0) >> 17) * DD + q * 8);
        f16x8 e1 = *(const f16x8*)(ctab + (((unsigned)r1) >> 17) * DD + q * 8);
        f16x8 e2 = *(const f16x8*)(ctab + (((unsigned)r2) >> 17) * DD + q * 8);
        f16x8 e3 = *(const f16x8*)(ctab + (((unsigned)r3) >> 17) * DD + q * 8);
        #pragma unroll
        for (int j = 0; j < 8; ++j) {
            float sc = (j < 4) ? sc0[j] : sc1[j - 4];
            float sh = (j < 4) ? sh0[j] : sh1[j - 4];
            float t0 = (float)y0[j] * sc + sh;
            float t1 = (float)y1[j] * sc + sh;
            float t2 = (float)y2[j] * sc + sh;
            float t3 = (float)y3[j] * sc + sh;
            if (dorelu) {
                if (t0 < 0.f) t0 = 0.f; if (t1 < 0.f) t1 = 0.f;
                if (t2 < 0.f) t2 = 0.f; if (t3 < 0.f) t3 = 0.f;
            }
            v[j] += (t0 + t1) + (t2 + t3)
                  + ((float)e0[j] + (float)e1[j]) + ((float)e2[j] + (float)e3[j]);
        }
    }
    for (; p < p1; ++p) {
        int r = rec[p];
        int s = r & 0x1FFFF;
        int f = ((unsigned)r) >> 17;
        f16x8 y = *(const f16x8*)(hsrc + s * DD + q * 8);
        f16x8 e = *(const f16x8*)(ctab + f * DD + q * 8);
        #pragma unroll
        for (int j = 0; j < 8; ++j) {
            float sc = (j < 4) ? sc0[j] : sc1[j - 4];
            float sh = (j < 4) ? sh0[j] : sh1[j - 4];
            float t = (float)y[j] * sc + sh;
            if (dorelu && t < 0.f) t = 0.f;
            v[j] += t + (float)e[j];
        }
    }
    f16x8 o;
    #pragma unroll
    for (int j = 0; j < 8; ++j) o[j] = (_Float16)v[j];
    ((f16x8*)agg)[idx] = o;
}

// ---------------- fused MLP v5: R4 structure + swapped GEMM1 + b64 hid writes
// GEMM1 as mfma(w1frag, aggfrag): node lands on lane&15, n1 on quad*4+reg, so
// the 4 values per nt are 4 consecutive columns of ONE hid row -> a single
// packed ds_write_b64 (2-way bank pattern = free) instead of 4 ds_write_u16.
// GEMM2 + epilogue identical to the measured-best R4 kernel.
__global__ __launch_bounds__(256) void mlp_kernel(
    const _Float16* __restrict__ A, const _Float16* __restrict__ w1t,
    const _Float16* __restrict__ w2t,
    const float* __restrict__ b1, const float* __restrict__ b2,
    _Float16* __restrict__ hpre, float* __restrict__ psum, float* __restrict__ psq,
    int M)
{
    __shared__ _Float16 w1c[64 * 136];   // chunk rows n1 (64), k=0..127 (+8 pad)
    __shared__ _Float16 w2c[128 * 72];   // rows n2 (128), k2 chunk 64 (+8 pad)
    __shared__ _Float16 hid[4 * 16 * 72]; // per-wave 16 nodes x (64+8 pad)
    __shared__ float red[1024];          // cross-wave stat reduce
    int tid = threadIdx.x;
    int wave = tid >> 6, lane = tid & 63;
    int ln = lane & 15, quad = lane >> 4;
    int wrow0 = blockIdx.x * 64 + wave * 16;
    int m = wrow0 + ln;
    bool valid = m < M;
    _Float16* hw = &hid[wave * 16 * 72];

    f16x8 af[4];
    #pragma unroll
    for (int kb = 0; kb < 4; ++kb) {
        f16x8 a = {};
        if (valid) a = *(const f16x8*)(A + m * 128 + kb * 32 + quad * 8);
        af[kb] = a;
    }

    f32x4 acc2[8] = {};
    for (int nc = 0; nc < 4; ++nc) {
        __syncthreads();
        for (int i = tid; i < 1024; i += 256) {  // w1c: 64 rows x 16 chunks
            int r = i >> 4, c = i & 15;
            *(f16x8*)(&w1c[r * 136 + c * 8]) =
                *(const f16x8*)(w1t + (nc * 64 + r) * 128 + c * 8);
        }
        for (int i = tid; i < 1024; i += 256) {  // w2c: 128 rows x 8 chunks
            int r = i >> 3, c = i & 7;
            *(f16x8*)(&w2c[r * 72 + c * 8]) =
                *(const f16x8*)(w2t + r * 256 + nc * 64 + c * 8);
        }
        __syncthreads();

        // GEMM1 swapped: lane(ln,quad) accumulates hid[node ln][n1=nt*16+quad*4+r]
        f32x4 acc1[4] = {};
        #pragma unroll
        for (int kb = 0; kb < 4; ++kb) {
            #pragma unroll
            for (int nt = 0; nt < 4; ++nt) {
                f16x8 wf = *(const f16x8*)(&w1c[(nt * 16 + ln) * 136 + kb * 32 + quad * 8]);
                acc1[nt] = __builtin_amdgcn_mfma_f32_16x16x32_f16(wf, af[kb], acc1[nt], 0, 0, 0);
            }
        }
        // bias + relu + packed b64 write into hid row ln
        #pragma unroll
        for (int nt = 0; nt < 4; ++nt) {
            f32x4 bb = *(const f32x4*)(b1 + nc * 64 + nt * 16 + quad * 4);
            f16x4 hv;
            #pragma unroll
            for (int r = 0; r < 4; ++r) {
                float v = acc1[nt][r] + bb[r];
                v = v > 0.f ? v : 0.f;
                hv[r] = (_Float16)v;
            }
            *(f16x4*)(&hw[ln * 72 + nt * 16 + quad * 4]) = hv;
        }
        // GEMM2: acc2 += hid_chunk @ W2[chunk, :]  (identical to R4)
        #pragma unroll
        for (int kb2 = 0; kb2 < 2; ++kb2) {
            f16x8 a2 = *(const f16x8*)(&hw[ln * 72 + kb2 * 32 + quad * 8]);
            #pragma unroll
            for (int nt2 = 0; nt2 < 8; ++nt2) {
                f16x8 wf = *(const f16x8*)(&w2c[(nt2 * 16 + ln) * 72 + kb2 * 32 + quad * 8]);
                acc2[nt2] = __builtin_amdgcn_mfma_f32_16x16x32_f16(a2, wf, acc2[nt2], 0, 0, 0);
            }
        }
    }

    // epilogue: bias, store hpre, per-block column partial sums (no atomics)
    #pragma unroll
    for (int nt2 = 0; nt2 < 8; ++nt2) {
        int n2 = nt2 * 16 + ln;
        float bias = b2[n2];
        float s = 0.f, q = 0.f;
        #pragma unroll
        for (int r = 0; r < 4; ++r) {
            int row = wrow0 + quad * 4 + r;
            if (row < M) {
                float v = acc2[nt2][r] + bias;
                hpre[row * 128 + n2] = (_Float16)v;
                s += v; q += v * v;
            }
        }
        s += __shfl_xor(s, 16, 64); s += __shfl_xor(s, 32, 64);
        q += __shfl_xor(q, 16, 64); q += __shfl_xor(q, 32, 64);
        if (quad == 0) {
            red[wave * 128 + n2] = s;
            red[512 + wave * 128 + n2] = q;
        }
    }
    __syncthreads();
    if (tid < 128) {
        float s = red[tid] + red[128 + tid] + red[256 + tid] + red[384 + tid];
        psum[blockIdx.x * 128 + tid] = s;
    } else {
        int c = tid - 128;
        float q = red[512 + c] + red[640 + c] + red[768 + c] + red[896 + c];
        psq[blockIdx.x * 128 + c] = q;
    }
}

// ---------------- fold partials -> scale/shift for BN ----------------
__global__ __launch_bounds__(256) void reduce_kernel(
    const float* __restrict__ psum, const float* __restrict__ psq,
    const float* __restrict__ gamma, const float* __restrict__ beta,
    float* __restrict__ ss, int nblk)
{
    int c = blockIdx.x;                  // 0..127
    int tid = threadIdx.x;
    float s = 0.f, q = 0.f;
    for (int b = tid; b < nblk; b += 256) {
        s += psum[b * 128 + c];
        q += psq[b * 128 + c];
    }
    #pragma unroll
    for (int off = 1; off < 64; off <<= 1) {
        s += __shfl_xor(s, off, 64);
        q += __shfl_xor(q, off, 64);
    }
    __shared__ float rs[4], rq[4];
    int wave = tid >> 6;
    if ((tid & 63) == 0) { rs[wave] = s; rq[wave] = q; }
    __syncthreads();
    if (tid == 0) {
        s = rs[0] + rs[1] + rs[2] + rs[3];
        q = rq[0] + rq[1] + rq[2] + rq[3];
        const float invN = 1.0f / NN;
        float mean = s * invN;
        float var = q * invN - mean * mean;
        float inv = rsqrtf(var + 1e-5f);
        float scale = gamma[c] * inv;
        ss[c] = scale;
        ss[128 + c] = beta[c] - mean * scale;
    }
}

// ---------------- final BN apply (no relu) -> fp32 d_out ----------------
__global__ __launch_bounds__(256) void final_bn_kernel(
    const _Float16* __restrict__ hpre, float* __restrict__ out,
    const float* __restrict__ ss)
{
    int idx = blockIdx.x * 256 + threadIdx.x;   // NN*16
    int q = idx & 15;
    f16x8 x = ((const f16x8*)hpre)[idx];
    f32x4 sc0 = ((const f32x4*)ss)[2 * q],        sc1 = ((const f32x4*)ss)[2 * q + 1];
    f32x4 sh0 = ((const f32x4*)(ss + 128))[2 * q], sh1 = ((const f32x4*)(ss + 128))[2 * q + 1];
    f32x4 y0, y1;
    #pragma unroll
    for (int j = 0; j < 4; ++j) {
        y0[j] = (float)x[j] * sc0[j] + sh0[j];
        y1[j] = (float)x[j + 4] * sc1[j] + sh1[j];
    }
    ((f32x4*)out)[2 * idx] = y0;
    ((f32x4*)out)[2 * idx + 1] = y1;
}

extern "C" void kernel_launch(void* const* d_in, const int* in_sizes, int n_in,
                              void* d_out, int out_size, void* d_ws, size_t ws_size,
                              hipStream_t stream)
{
    const int* an  = (const int*)d_in[0];
    const int* fc  = (const int*)d_in[1];
    const int* ct  = (const int*)d_in[2];
    const int* hy  = (const int*)d_in[3];
    const int* nh  = (const int*)d_in[4];
    const int* ar  = (const int*)d_in[5];
    const int* ei  = (const int*)d_in[6];
    const int* econ = (const int*)d_in[7];
    const int* earo = (const int*)d_in[8];
    const int* ebt  = (const int*)d_in[9];
    const int* ebd  = (const int*)d_in[10];
    const int* ebs  = (const int*)d_in[11];
    const float* ean = (const float*)d_in[12];
    const float* efc = (const float*)d_in[13];
    const float* ect = (const float*)d_in[14];
    const float* ehy = (const float*)d_in[15];
    const float* enh = (const float*)d_in[16];
    const float* ear = (const float*)d_in[17];
    const float* e_conj   = (const float*)d_in[18];
    const float* e_arom   = (const float*)d_in[19];
    const float* e_btype  = (const float*)d_in[20];
    const float* e_bdir   = (const float*)d_in[21];
    const float* e_bstereo= (const float*)d_in[22];
    const float* mlp_w1 = (const float*)d_in[23];
    const float* mlp_b1 = (const float*)d_in[24];
    const float* mlp_w2 = (const float*)d_in[25];
    const float* mlp_b2 = (const float*)d_in[26];
    const float* bn_gamma = (const float*)d_in[27];
    const float* bn_beta  = (const float*)d_in[28];

    // workspace carve (base 256B-aligned; all segments stay 16B-aligned)
    _Float16* h0    = (_Float16*)d_ws;                  // N*128 fp16
    _Float16* agg   = h0 + (size_t)NN * DD;             // N*128 fp16
    _Float16* hpre  = agg + (size_t)NN * DD;            // N*128 fp16
    _Float16* w1t   = hpre + (size_t)NN * DD;           // 5*256*128 fp16
    _Float16* w2t   = w1t + LL * 256 * 128;             // 5*128*256 fp16
    _Float16* ctabL = w2t + LL * 128 * 256;             // LL*CTROWS*128 fp16
    float*    psum  = (float*)(ctabL + (size_t)LL * CTROWS * DD);  // MBLK*128
    float*    psq   = psum + MBLK * 128;                // MBLK*128
    float*    ss    = psq + MBLK * 128;                 // 256 (scale|shift)
    float*    idss  = ss + 256;                         // 256 identity
    int* rowstart = (int*)(idss + 256);                 // NN+1
    int* cursor   = rowstart + NN + 8;                  // NN
    int* rec      = cursor + NN;                        // EE
    int* btot     = rec + EE;                           // SBLK
    int* boff     = btot + SBLK + 8;                    // SBLK
    // total ~= 93 MB

    convw_kernel<<<1280, 256, 0, stream>>>(mlp_w1, mlp_w2, w1t, w2t);
    seed_kernel<<<6250, 256, 0, stream>>>(an, fc, ct, hy, nh, ar,
                                          ean, efc, ect, ehy, enh, ear, h0);
    idss_kernel<<<1, 256, 0, stream>>>(idss);
    ctab_kernel<<<1610, 256, 0, stream>>>(e_conj, e_arom, e_btype, e_bdir,
                                          e_bstereo, ctabL);

    // CSR build (re-run every call: ws is re-poisoned)
    hipMemsetAsync(cursor, 0, NN * sizeof(int), stream);
    count_kernel<<<2344, 256, 0, stream>>>(ei, cursor);
    btot_kernel<<<SBLK, 1024, 0, stream>>>(cursor, btot);
    bscan_kernel<<<1, 128, 0, stream>>>(btot, boff, rowstart);
    apply_kernel<<<SBLK, 1024, 0, stream>>>(cursor, boff, rowstart, cursor);
    fill_kernel<<<2344, 256, 0, stream>>>(ei, cursor, rec,
                                          econ, earo, ebt, ebd, ebs);

    for (int l = 0; l < LL; ++l) {
        gather_bn_kernel<<<6250, 256, 0, stream>>>(
            (l == 0) ? h0 : hpre, agg, rowstart, rec,
            ctabL + (size_t)l * CTROWS * DD,
            (l == 0) ? idss : ss, (l == 0) ? 0 : 1);
        mlp_kernel<<<MBLK, 256, 0, stream>>>(
            agg, w1t + l * 32768, w2t + l * 32768,
            mlp_b1 + l * 256, mlp_b2 + l * 128,
            hpre, psum, psq, NN);
        reduce_kernel<<<128, 256, 0, stream>>>(
            psum, psq, bn_gamma + l * 128, bn_beta + l * 128, ss, MBLK);
    }
    final_bn_kernel<<<6250, 256, 0, stream>>>(hpre, (float*)d_out, ss);
}